// Round 1
// baseline (3215.919 us; speedup 1.0000x reference)
//
#include <hip/hip_runtime.h>
#include <math.h>

// Problem constants (from reference): B=2, S=2048, U=1024, H=16, DK=64
#define B_NUM 2
#define S_LEN 2048
#define U_DIM 1024
#define H_NUM 16
#define DK 64

// ---------------------------------------------------------------------------
// GEMM: C[M,N] = A[M,K] @ W[N,K]^T + bias[N]   (torch Linear convention)
// Both A and W are read contiguously along K (NT layout — favorable).
// BM=BN=64, BK=32, 256 threads, 4x4 micro-tile per thread.
// ---------------------------------------------------------------------------
constexpr int BM = 64, BN = 64, BK = 32;

__global__ __launch_bounds__(256) void gemm_nt_bias(
    const float* __restrict__ A, const float* __restrict__ W,
    const float* __restrict__ bias, float* __restrict__ C,
    int M, int N, int K)
{
    // +1 pad: compute-phase reads become broadcast or 2-way (free per m136)
    __shared__ float As[BM][BK + 1];
    __shared__ float Ws[BN][BK + 1];

    const int tid = threadIdx.x;
    const int tx = tid & 15;   // column group 0..15
    const int ty = tid >> 4;   // row group 0..15
    const int rowBase = blockIdx.y * BM;
    const int colBase = blockIdx.x * BN;

    float acc[4][4] = {};

    for (int k0 = 0; k0 < K; k0 += BK) {
        // Stage 64x32 tiles of A and W. 512 float4 per tile -> 2 per thread.
#pragma unroll
        for (int t = 0; t < 2; ++t) {
            int f = tid + t * 256;       // 0..511
            int m = f >> 3;              // 0..63
            int c = (f & 7) * 4;         // 0,4,...,28
            float4 av = *(const float4*)&A[(size_t)(rowBase + m) * K + k0 + c];
            float4 wv = *(const float4*)&W[(size_t)(colBase + m) * K + k0 + c];
            As[m][c + 0] = av.x; As[m][c + 1] = av.y;
            As[m][c + 2] = av.z; As[m][c + 3] = av.w;
            Ws[m][c + 0] = wv.x; Ws[m][c + 1] = wv.y;
            Ws[m][c + 2] = wv.z; Ws[m][c + 3] = wv.w;
        }
        __syncthreads();

#pragma unroll
        for (int k = 0; k < BK; ++k) {
            float a[4], w[4];
#pragma unroll
            for (int i = 0; i < 4; ++i) a[i] = As[ty * 4 + i][k];
#pragma unroll
            for (int j = 0; j < 4; ++j) w[j] = Ws[tx * 4 + j][k];
#pragma unroll
            for (int i = 0; i < 4; ++i)
#pragma unroll
                for (int j = 0; j < 4; ++j)
                    acc[i][j] = fmaf(a[i], w[j], acc[i][j]);
        }
        __syncthreads();
    }

    // Epilogue: add bias, vectorized float4 stores
    const int col0 = colBase + tx * 4;
    float4 bv = *(const float4*)&bias[col0];
#pragma unroll
    for (int i = 0; i < 4; ++i) {
        int row = rowBase + ty * 4 + i;
        float4 r;
        r.x = acc[i][0] + bv.x;
        r.y = acc[i][1] + bv.y;
        r.z = acc[i][2] + bv.z;
        r.w = acc[i][3] + bv.w;
        *(float4*)&C[(size_t)row * N + col0] = r;
    }
}

// ---------------------------------------------------------------------------
// Causal flash attention, fp32, one wave (64 lanes) per query row.
// Q,K,V,O all in [B, S, U] layout; head h occupies columns [h*64, h*64+64).
// Phase A: lane = key index within a 64-wide K-block (q staged in LDS).
// Phase B: lane = head dim d; P broadcast from LDS; coalesced V reads.
// ---------------------------------------------------------------------------
__global__ __launch_bounds__(64) void flash_attn(
    const float* __restrict__ Q, const float* __restrict__ K,
    const float* __restrict__ V, float* __restrict__ O)
{
    const int qi = blockIdx.x;       // 0..S-1
    const int h  = blockIdx.y;       // 0..H-1
    const int b  = blockIdx.z;       // 0..B-1
    const int lane = threadIdx.x;    // 0..63

    __shared__ float q_s[DK];
    __shared__ float p_s[64];

    const size_t base = ((size_t)b * S_LEN) * U_DIM + h * DK;
    // fold the 1/sqrt(DK)=0.125 score scale into q
    q_s[lane] = Q[base + (size_t)qi * U_DIM + lane] * 0.125f;
    __syncthreads();

    float m = -INFINITY, l = 0.0f, acc = 0.0f;
    const int nkb = (qi >> 6) + 1;   // causal: K-blocks 0..floor(qi/64)

    const float* Kb = K + base;
    const float* Vb = V + base;

    for (int kb = 0; kb < nkb; ++kb) {
        const int krow = kb * 64 + lane;

        // ---- Phase A: score for this lane's key row ----
        float s;
        {
            const float4* k4 = (const float4*)(Kb + (size_t)krow * U_DIM);
            const float4* q4 = (const float4*)q_s;
            float sum = 0.0f;
#pragma unroll
            for (int i = 0; i < DK / 4; ++i) {
                float4 kv = k4[i];
                float4 qv = q4[i];
                sum = fmaf(qv.x, kv.x, sum);
                sum = fmaf(qv.y, kv.y, sum);
                sum = fmaf(qv.z, kv.z, sum);
                sum = fmaf(qv.w, kv.w, sum);
            }
            s = (krow <= qi) ? sum : -INFINITY;
        }

        // ---- online softmax (64-lane butterfly reductions) ----
        float mb = s;
#pragma unroll
        for (int off = 32; off > 0; off >>= 1)
            mb = fmaxf(mb, __shfl_xor(mb, off));
        const float m_new = fmaxf(m, mb);           // finite: lane 0 always valid
        const float p = __expf(s - m_new);          // masked lanes -> exp(-inf)=0
        float sp = p;
#pragma unroll
        for (int off = 32; off > 0; off >>= 1)
            sp += __shfl_xor(sp, off);
        const float alpha = __expf(m - m_new);      // first iter: exp(-inf)=0
        l = l * alpha + sp;

        __syncthreads();
        p_s[lane] = p;
        __syncthreads();

        // ---- Phase B: lane = output dim d; coalesced V reads ----
        acc *= alpha;
        const float* vrow = Vb + (size_t)(kb * 64) * U_DIM + lane;
        const int jmax = min(64, qi - kb * 64 + 1);
        for (int j = 0; j < jmax; ++j)
            acc = fmaf(p_s[j], vrow[(size_t)j * U_DIM], acc);

        m = m_new;
    }

    O[base + (size_t)qi * U_DIM + lane] = acc / l;
}

// ---------------------------------------------------------------------------
// Launch: 3 projection GEMMs -> flash attention -> output GEMM.
// Workspace: q(16MB) | k(16MB) | v(16MB) | attn_out(16MB), all fully
// overwritten before read (safe under 0xAA re-poison).
// Input order: query,key,value,mask,Wq,bq,Wk,bk,Wv,bv,Wo,bo. Mask ignored
// (known causal tril).
// ---------------------------------------------------------------------------
extern "C" void kernel_launch(void* const* d_in, const int* in_sizes, int n_in,
                              void* d_out, int out_size, void* d_ws, size_t ws_size,
                              hipStream_t stream)
{
    const float* query = (const float*)d_in[0];
    const float* key   = (const float*)d_in[1];
    const float* value = (const float*)d_in[2];
    const float* Wq = (const float*)d_in[4];
    const float* bq = (const float*)d_in[5];
    const float* Wk = (const float*)d_in[6];
    const float* bk = (const float*)d_in[7];
    const float* Wv = (const float*)d_in[8];
    const float* bv = (const float*)d_in[9];
    const float* Wo = (const float*)d_in[10];
    const float* bo = (const float*)d_in[11];
    float* out = (float*)d_out;

    const int M = B_NUM * S_LEN;   // 4096
    const int N = U_DIM;           // 1024
    const int Kd = U_DIM;          // 1024

    float* q_ws = (float*)d_ws;
    float* k_ws = q_ws + (size_t)M * N;
    float* v_ws = k_ws + (size_t)M * N;
    float* a_ws = v_ws + (size_t)M * N;

    dim3 ggrid(N / BN, M / BM);    // (16, 64)
    gemm_nt_bias<<<ggrid, 256, 0, stream>>>(query, Wq, bq, q_ws, M, N, Kd);
    gemm_nt_bias<<<ggrid, 256, 0, stream>>>(key,   Wk, bk, k_ws, M, N, Kd);
    gemm_nt_bias<<<ggrid, 256, 0, stream>>>(value, Wv, bv, v_ws, M, N, Kd);

    flash_attn<<<dim3(S_LEN, H_NUM, B_NUM), 64, 0, stream>>>(q_ws, k_ws, v_ws, a_ws);

    gemm_nt_bias<<<ggrid, 256, 0, stream>>>(a_ws, Wo, bo, out, M, N, Kd);
}

// Round 2
// 931.508 us; speedup vs baseline: 3.4524x; 3.4524x over previous
//
#include <hip/hip_runtime.h>
#include <math.h>

// Problem constants: B=2, S=2048, U=1024, H=16, DK=64
#define B_NUM 2
#define S_LEN 2048
#define U_DIM 1024
#define H_NUM 16
#define DK 64

typedef __attribute__((ext_vector_type(8))) short bf8;   // 8 bf16 = 4 VGPRs (MFMA A/B frag)
typedef __attribute__((ext_vector_type(4))) float f4;    // MFMA C/D frag

// float -> bf16 (round to nearest even), as raw ushort bits
__device__ inline unsigned short f2bf(float f) {
    union { float f; unsigned int u; } x; x.f = f;
    unsigned int r = x.u + 0x7fffu + ((x.u >> 16) & 1u);
    return (unsigned short)(r >> 16);
}

// ---------------------------------------------------------------------------
// GEMM: C[M,N] = A[M,K] @ W[N,K]^T + bias[N]  (fp32, unchanged from R1)
// ---------------------------------------------------------------------------
constexpr int BM = 64, BN = 64, BK = 32;

__global__ __launch_bounds__(256) void gemm_nt_bias(
    const float* __restrict__ A, const float* __restrict__ W,
    const float* __restrict__ bias, float* __restrict__ C,
    int M, int N, int K)
{
    __shared__ float As[BM][BK + 1];
    __shared__ float Ws[BN][BK + 1];

    const int tid = threadIdx.x;
    const int tx = tid & 15;
    const int ty = tid >> 4;
    const int rowBase = blockIdx.y * BM;
    const int colBase = blockIdx.x * BN;

    float acc[4][4] = {};

    for (int k0 = 0; k0 < K; k0 += BK) {
#pragma unroll
        for (int t = 0; t < 2; ++t) {
            int f = tid + t * 256;
            int m = f >> 3;
            int c = (f & 7) * 4;
            float4 av = *(const float4*)&A[(size_t)(rowBase + m) * K + k0 + c];
            float4 wv = *(const float4*)&W[(size_t)(colBase + m) * K + k0 + c];
            As[m][c + 0] = av.x; As[m][c + 1] = av.y;
            As[m][c + 2] = av.z; As[m][c + 3] = av.w;
            Ws[m][c + 0] = wv.x; Ws[m][c + 1] = wv.y;
            Ws[m][c + 2] = wv.z; Ws[m][c + 3] = wv.w;
        }
        __syncthreads();

#pragma unroll
        for (int k = 0; k < BK; ++k) {
            float a[4], w[4];
#pragma unroll
            for (int i = 0; i < 4; ++i) a[i] = As[ty * 4 + i][k];
#pragma unroll
            for (int j = 0; j < 4; ++j) w[j] = Ws[tx * 4 + j][k];
#pragma unroll
            for (int i = 0; i < 4; ++i)
#pragma unroll
                for (int j = 0; j < 4; ++j)
                    acc[i][j] = fmaf(a[i], w[j], acc[i][j]);
        }
        __syncthreads();
    }

    const int col0 = colBase + tx * 4;
    float4 bv = *(const float4*)&bias[col0];
#pragma unroll
    for (int i = 0; i < 4; ++i) {
        int row = rowBase + ty * 4 + i;
        float4 r;
        r.x = acc[i][0] + bv.x;
        r.y = acc[i][1] + bv.y;
        r.z = acc[i][2] + bv.z;
        r.w = acc[i][3] + bv.w;
        *(float4*)&C[(size_t)row * N + col0] = r;
    }
}

// ---------------------------------------------------------------------------
// Transpose+convert V: fp32 [b, s, h*64+d] -> bf16 VT[((b*H+h)*64+d)*S + s]
// Coalesced in and out via fp32 LDS tile.
// ---------------------------------------------------------------------------
__global__ __launch_bounds__(256) void transpose_v_bf16(
    const float* __restrict__ V, unsigned short* __restrict__ VT)
{
    __shared__ float tile[64][65];
    const int s0 = blockIdx.x * 64;
    const int h  = blockIdx.y;
    const int b  = blockIdx.z;
    const int tid = threadIdx.x;
    const int rowi = tid >> 4, c4 = (tid & 15) * 4;

#pragma unroll
    for (int p = 0; p < 4; ++p) {
        int tok = p * 16 + rowi;
        float4 v = *(const float4*)&V[((size_t)b * S_LEN + s0 + tok) * U_DIM + h * DK + c4];
        tile[tok][c4 + 0] = v.x; tile[tok][c4 + 1] = v.y;
        tile[tok][c4 + 2] = v.z; tile[tok][c4 + 3] = v.w;
    }
    __syncthreads();

    const int lane = tid & 63, dg = tid >> 6;
#pragma unroll
    for (int i = 0; i < 16; ++i) {
        int d = dg * 16 + i;
        VT[((size_t)(b * H_NUM + h) * DK + d) * S_LEN + s0 + lane] = f2bf(tile[lane][d]);
    }
}

// ---------------------------------------------------------------------------
// MFMA flash attention (bf16 inputs, fp32 softmax+accum).
// Block: 64 q-rows × one (b,h). 4 waves; wave w owns q-rows w*16..w*16+15.
// K-blocks of 64 keys; causal => kb in [0, q0/64].
// LDS rows padded to 72 bf16 (144 B): frag ds_read_b128 16B-aligned,
// (lane&15)+quad spreads across all 8 4-bank groups (conflict-free).
// ---------------------------------------------------------------------------
#define LDP 72

__global__ __launch_bounds__(256, 4) void attn_mfma(
    const float* __restrict__ Q, const float* __restrict__ K,
    const unsigned short* __restrict__ VT, float* __restrict__ O)
{
    __shared__ unsigned short Qs[64][LDP];
    __shared__ unsigned short Ks[64][LDP];
    __shared__ unsigned short Vs[64][LDP];      // [d][key]
    __shared__ unsigned short Ps[4][16][LDP];   // per-wave P tile [qrow][key]

    const int qt = (int)gridDim.x - 1 - (int)blockIdx.x;  // heaviest tiles first
    const int q0 = qt * 64;
    const int h  = blockIdx.y;
    const int b  = blockIdx.z;
    const int tid  = threadIdx.x;
    const int w    = tid >> 6;        // wave 0..3
    const int lane = tid & 63;
    const int quad = lane >> 4;       // 0..3
    const int cid  = lane & 15;       // 0..15

    const int rowi = tid >> 4;        // staging: 0..15
    const int c4   = (tid & 15) * 4;

    // ---- stage Q tile (scale 1/sqrt(DK)=0.125 folded in before rounding) ----
#pragma unroll
    for (int p = 0; p < 4; ++p) {
        int tok = p * 16 + rowi;
        float4 v = *(const float4*)&Q[((size_t)b * S_LEN + q0 + tok) * U_DIM + h * DK + c4];
        Qs[tok][c4 + 0] = f2bf(v.x * 0.125f);
        Qs[tok][c4 + 1] = f2bf(v.y * 0.125f);
        Qs[tok][c4 + 2] = f2bf(v.z * 0.125f);
        Qs[tok][c4 + 3] = f2bf(v.w * 0.125f);
    }
    __syncthreads();

    bf8 qf0 = *(const bf8*)&Qs[w * 16 + cid][quad * 8];
    bf8 qf1 = *(const bf8*)&Qs[w * 16 + cid][32 + quad * 8];

    f4 o[4] = {};            // O accumulator: 4 d-tiles × 4 rows (C layout)
    float m_i[4], l_i[4];
#pragma unroll
    for (int i = 0; i < 4; ++i) { m_i[i] = -INFINITY; l_i[i] = 0.0f; }

    const int lastkb = q0 >> 6;
    const unsigned short* vt_head = VT + (size_t)(b * H_NUM + h) * DK * S_LEN;

    for (int kb = 0; kb <= lastkb; ++kb) {
        __syncthreads();   // all waves done reading previous Ks/Vs

        // ---- stage K tile [key][d] fp32->bf16, coalesced ----
#pragma unroll
        for (int p = 0; p < 4; ++p) {
            int key = p * 16 + rowi;
            float4 v = *(const float4*)&K[((size_t)b * S_LEN + kb * 64 + key) * U_DIM + h * DK + c4];
            Ks[key][c4 + 0] = f2bf(v.x);
            Ks[key][c4 + 1] = f2bf(v.y);
            Ks[key][c4 + 2] = f2bf(v.z);
            Ks[key][c4 + 3] = f2bf(v.w);
        }
        // ---- stage V^T tile [d][key] bf16, coalesced 16B loads/stores ----
        {
            int d = tid >> 2, seg = tid & 3;
            const unsigned short* src = vt_head + (size_t)d * S_LEN + kb * 64 + seg * 16;
            uint4 a0 = *(const uint4*)(src);
            uint4 a1 = *(const uint4*)(src + 8);
            *(uint4*)&Vs[d][seg * 16]     = a0;
            *(uint4*)&Vs[d][seg * 16 + 8] = a1;
        }
        __syncthreads();

        // ---- scores S = Q K^T : 4 n-tiles × 2 k-steps ----
        f4 sc[4];
#pragma unroll
        for (int t = 0; t < 4; ++t) {
            bf8 k0 = *(const bf8*)&Ks[t * 16 + cid][quad * 8];
            bf8 k1 = *(const bf8*)&Ks[t * 16 + cid][32 + quad * 8];
            f4 acc = {};
            acc = __builtin_amdgcn_mfma_f32_16x16x32_bf16(qf0, k0, acc, 0, 0, 0);
            acc = __builtin_amdgcn_mfma_f32_16x16x32_bf16(qf1, k1, acc, 0, 0, 0);
            sc[t] = acc;
        }

        // ---- causal mask (only the diagonal block is partial) ----
        if (kb == lastkb) {
#pragma unroll
            for (int t = 0; t < 4; ++t) {
                int col = kb * 64 + t * 16 + cid;
#pragma unroll
                for (int i = 0; i < 4; ++i) {
                    int row = q0 + w * 16 + quad * 4 + i;
                    if (col > row) sc[t][i] = -1e30f;
                }
            }
        }

        // ---- online softmax per row (butterfly over the 16 col-lanes) ----
        float alpha_[4];
#pragma unroll
        for (int i = 0; i < 4; ++i) {
            float mx = fmaxf(fmaxf(sc[0][i], sc[1][i]), fmaxf(sc[2][i], sc[3][i]));
            mx = fmaxf(mx, __shfl_xor(mx, 1));
            mx = fmaxf(mx, __shfl_xor(mx, 2));
            mx = fmaxf(mx, __shfl_xor(mx, 4));
            mx = fmaxf(mx, __shfl_xor(mx, 8));
            float mnew = fmaxf(m_i[i], mx);
            alpha_[i] = __expf(m_i[i] - mnew);   // first block: exp(-inf)=0
            m_i[i] = mnew;
            float rs = 0.0f;
#pragma unroll
            for (int t = 0; t < 4; ++t) {
                float p = __expf(sc[t][i] - mnew);
                sc[t][i] = p;
                rs += p;
            }
            rs += __shfl_xor(rs, 1);
            rs += __shfl_xor(rs, 2);
            rs += __shfl_xor(rs, 4);
            rs += __shfl_xor(rs, 8);
            l_i[i] = l_i[i] * alpha_[i] + rs;
        }

        // ---- P: C-layout -> LDS -> A-layout fragments (per-wave region) ----
#pragma unroll
        for (int t = 0; t < 4; ++t)
#pragma unroll
            for (int i = 0; i < 4; ++i)
                Ps[w][quad * 4 + i][t * 16 + cid] = f2bf(sc[t][i]);

        bf8 p0 = *(const bf8*)&Ps[w][cid][quad * 8];
        bf8 p1 = *(const bf8*)&Ps[w][cid][32 + quad * 8];

        // ---- O = O*alpha + P V ----
#pragma unroll
        for (int t = 0; t < 4; ++t) {
#pragma unroll
            for (int i = 0; i < 4; ++i) o[t][i] *= alpha_[i];
            bf8 v0 = *(const bf8*)&Vs[t * 16 + cid][quad * 8];
            bf8 v1 = *(const bf8*)&Vs[t * 16 + cid][32 + quad * 8];
            o[t] = __builtin_amdgcn_mfma_f32_16x16x32_bf16(p0, v0, o[t], 0, 0, 0);
            o[t] = __builtin_amdgcn_mfma_f32_16x16x32_bf16(p1, v1, o[t], 0, 0, 0);
        }
    }

    // ---- epilogue: O / l, fp32 out in [b,s,u] layout ----
#pragma unroll
    for (int i = 0; i < 4; ++i) {
        float inv = 1.0f / l_i[i];
        int rowg = q0 + w * 16 + quad * 4 + i;
        size_t rbase = ((size_t)b * S_LEN + rowg) * U_DIM + h * DK;
#pragma unroll
        for (int t = 0; t < 4; ++t)
            O[rbase + t * 16 + cid] = o[t][i] * inv;
    }
}

// ---------------------------------------------------------------------------
// Workspace: q(16M) | k(16M) | v(16M) | attn_out(16M) | vt bf16 (8M) = 72 MB.
// All regions fully overwritten before read (0xAA-poison safe).
// ---------------------------------------------------------------------------
extern "C" void kernel_launch(void* const* d_in, const int* in_sizes, int n_in,
                              void* d_out, int out_size, void* d_ws, size_t ws_size,
                              hipStream_t stream)
{
    const float* query = (const float*)d_in[0];
    const float* key   = (const float*)d_in[1];
    const float* value = (const float*)d_in[2];
    const float* Wq = (const float*)d_in[4];
    const float* bq = (const float*)d_in[5];
    const float* Wk = (const float*)d_in[6];
    const float* bk = (const float*)d_in[7];
    const float* Wv = (const float*)d_in[8];
    const float* bv = (const float*)d_in[9];
    const float* Wo = (const float*)d_in[10];
    const float* bo = (const float*)d_in[11];
    float* out = (float*)d_out;

    const int M = B_NUM * S_LEN;   // 4096
    const int N = U_DIM;
    const int Kd = U_DIM;

    float* q_ws = (float*)d_ws;
    float* k_ws = q_ws + (size_t)M * N;
    float* v_ws = k_ws + (size_t)M * N;
    float* a_ws = v_ws + (size_t)M * N;
    unsigned short* vt_ws = (unsigned short*)(a_ws + (size_t)M * N);

    dim3 ggrid(N / BN, M / BM);
    gemm_nt_bias<<<ggrid, 256, 0, stream>>>(query, Wq, bq, q_ws, M, N, Kd);
    gemm_nt_bias<<<ggrid, 256, 0, stream>>>(key,   Wk, bk, k_ws, M, N, Kd);
    gemm_nt_bias<<<ggrid, 256, 0, stream>>>(value, Wv, bv, v_ws, M, N, Kd);

    transpose_v_bf16<<<dim3(S_LEN / 64, H_NUM, B_NUM), 256, 0, stream>>>(v_ws, vt_ws);

    attn_mfma<<<dim3(S_LEN / 64, H_NUM, B_NUM), 256, 0, stream>>>(q_ws, k_ws, vt_ws, a_ws);

    gemm_nt_bias<<<ggrid, 256, 0, stream>>>(a_ws, Wo, bo, out, M, N, Kd);
}

// Round 3
// 312.457 us; speedup vs baseline: 10.2924x; 2.9812x over previous
//
#include <hip/hip_runtime.h>
#include <math.h>

// Problem constants: B=2, S=2048, U=1024, H=16, DK=64
#define B_NUM 2
#define S_LEN 2048
#define U_DIM 1024
#define H_NUM 16
#define DK 64
#define M_TOT (B_NUM * S_LEN)   // 4096

typedef __attribute__((ext_vector_type(8))) short bf8;   // 8 bf16 (MFMA A/B frag)
typedef __attribute__((ext_vector_type(4))) float f4;    // MFMA C/D frag

// float -> bf16 (round to nearest even), raw ushort bits
__device__ __forceinline__ unsigned short f2bf(float f) {
    union { float f; unsigned int u; } x; x.f = f;
    unsigned int r = x.u + 0x7fffu + ((x.u >> 16) & 1u);
    return (unsigned short)(r >> 16);
}

// async global->LDS, 16 B per lane; LDS dest = wave-uniform base + lane*16
__device__ __forceinline__ void gl2lds16(const void* g, void* l) {
    __builtin_amdgcn_global_load_lds(
        (const __attribute__((address_space(1))) unsigned int*)g,
        (__attribute__((address_space(3))) unsigned int*)l, 16, 0, 0);
}

// ---------------------------------------------------------------------------
// Bulk fp32 -> bf16 conversion. blockIdx.y selects one of 7 tensors.
// ---------------------------------------------------------------------------
struct CvtArgs {
    const float* src[7];
    unsigned short* dst[7];
    int n[7];
};

__global__ __launch_bounds__(256) void convert_bf16(CvtArgs a)
{
    const int seg = blockIdx.y;
    const int i = (blockIdx.x * 256 + threadIdx.x) * 8;
    if (i >= a.n[seg]) return;
    const float* s = a.src[seg] + i;
    float4 v0 = *(const float4*)s;
    float4 v1 = *(const float4*)(s + 4);
    unsigned int p0 = (unsigned)f2bf(v0.x) | ((unsigned)f2bf(v0.y) << 16);
    unsigned int p1 = (unsigned)f2bf(v0.z) | ((unsigned)f2bf(v0.w) << 16);
    unsigned int p2 = (unsigned)f2bf(v1.x) | ((unsigned)f2bf(v1.y) << 16);
    unsigned int p3 = (unsigned)f2bf(v1.z) | ((unsigned)f2bf(v1.w) << 16);
    uint4 o = {p0, p1, p2, p3};
    *(uint4*)(a.dst[seg] + i) = o;
}

// ---------------------------------------------------------------------------
// bf16 MFMA GEMM (m97 structure): C[M,N] = A[M,K] @ W[N,K]^T + bias, *scale.
// 128x128 tile, BK=32, 256 threads (4 waves in 2x2), global_load_lds staging.
// K-dim swizzle (seg=(quad+(row>>2))&3) folded into the staging source addr
// so frag ds_read_b128 is 2-way-max bank aliasing (free per m136).
// ---------------------------------------------------------------------------
template <typename OutT>
__device__ __forceinline__ void gemm_core(
    const unsigned short* __restrict__ A, const unsigned short* __restrict__ W,
    const float* __restrict__ bias, OutT* __restrict__ C, float scale)
{
    __shared__ __align__(16) unsigned short As[128][32];
    __shared__ __align__(16) unsigned short Bs[128][32];

    const int tid = threadIdx.x;
    const int w = tid >> 6, lane = tid & 63;
    const int quad = lane >> 4, cid = lane & 15;
    const int wy = w >> 1, wx = w & 1;
    const int m0 = blockIdx.y * 128, n0 = blockIdx.x * 128;

    // staging: 1 KB chunk = 16 rows x 64 B; wave w -> chunks 2w, 2w+1
    const int r0 = w * 32 + (lane >> 2);     // tile row (chunk 2w)
    const int r1 = r0 + 16;                  // tile row (chunk 2w+1)
    const int ps = lane & 3;                 // physical 16B segment
    const int sA0 = ((ps - (r0 >> 2)) & 3) * 8;   // logical bf16 col for phys slot
    const int sA1 = ((ps - (r1 >> 2)) & 3) * 8;

    const unsigned short* gA0 = A + (size_t)(m0 + r0) * U_DIM + sA0;
    const unsigned short* gA1 = A + (size_t)(m0 + r1) * U_DIM + sA1;
    const unsigned short* gB0 = W + (size_t)(n0 + r0) * U_DIM + sA0;
    const unsigned short* gB1 = W + (size_t)(n0 + r1) * U_DIM + sA1;

    f4 acc[4][4] = {};

    for (int k0 = 0; k0 < U_DIM; k0 += 32) {
        if (k0) __syncthreads();             // readers of previous tile done
        gl2lds16(gA0 + k0, &As[w * 32][0]);
        gl2lds16(gA1 + k0, &As[w * 32 + 16][0]);
        gl2lds16(gB0 + k0, &Bs[w * 32][0]);
        gl2lds16(gB1 + k0, &Bs[w * 32 + 16][0]);
        __syncthreads();                     // vmcnt drained by compiler

        bf8 af[4], bfr[4];
#pragma unroll
        for (int mt = 0; mt < 4; ++mt) {
            int row = wy * 64 + mt * 16 + cid;
            int seg = (quad + (row >> 2)) & 3;
            af[mt] = *(const bf8*)&As[row][seg * 8];
        }
#pragma unroll
        for (int nt = 0; nt < 4; ++nt) {
            int row = wx * 64 + nt * 16 + cid;
            int seg = (quad + (row >> 2)) & 3;
            bfr[nt] = *(const bf8*)&Bs[row][seg * 8];
        }
#pragma unroll
        for (int mt = 0; mt < 4; ++mt)
#pragma unroll
            for (int nt = 0; nt < 4; ++nt)
                acc[mt][nt] = __builtin_amdgcn_mfma_f32_16x16x32_bf16(
                    af[mt], bfr[nt], acc[mt][nt], 0, 0, 0);
    }

    // epilogue: bias, scale, store (C/D layout: col=cid, row=quad*4+i)
#pragma unroll
    for (int nt = 0; nt < 4; ++nt) {
        int col = n0 + wx * 64 + nt * 16 + cid;
        float bv = bias[col];
#pragma unroll
        for (int mt = 0; mt < 4; ++mt) {
            int rowb = m0 + wy * 64 + mt * 16 + quad * 4;
#pragma unroll
            for (int i = 0; i < 4; ++i) {
                float v = (acc[mt][nt][i] + bv) * scale;
                size_t idx = (size_t)(rowb + i) * U_DIM + col;
                if constexpr (sizeof(OutT) == 2) C[idx] = f2bf(v);
                else                             C[idx] = v;
            }
        }
    }
}

struct QkvArgs {
    const unsigned short* A[3];
    const unsigned short* W[3];
    const float* bias[3];
    unsigned short* C[3];
    float scale[3];
};

__global__ __launch_bounds__(256, 3) void gemm_qkv(QkvArgs a) {
    const int z = blockIdx.z;
    gemm_core<unsigned short>(a.A[z], a.W[z], a.bias[z], a.C[z], a.scale[z]);
}

__global__ __launch_bounds__(256, 3) void gemm_obf(
    const unsigned short* __restrict__ A, const unsigned short* __restrict__ W,
    const float* __restrict__ bias, float* __restrict__ C) {
    gemm_core<float>(A, W, bias, C, 1.0f);
}

// ---------------------------------------------------------------------------
// Transpose V (bf16): [b, s, h*64+d] -> VT[((b*H+h)*64+d)*S + s]
// ---------------------------------------------------------------------------
__global__ __launch_bounds__(256) void transpose_v(
    const unsigned short* __restrict__ Vb, unsigned short* __restrict__ VT)
{
    __shared__ __align__(16) unsigned short tile[64][68];  // 68: 2/4-way max
    const int s0 = blockIdx.x * 64, h = blockIdx.y, b = blockIdx.z;
    const int tid = threadIdx.x;
    const int row = tid >> 3;            // 0..31
    const int sg = (tid & 7) * 8;
#pragma unroll
    for (int p = 0; p < 2; ++p) {
        int tok = p * 32 + row;
        const unsigned short* src = &Vb[((size_t)b * S_LEN + s0 + tok) * U_DIM + h * DK + sg];
        uint2 v0 = *(const uint2*)src;
        uint2 v1 = *(const uint2*)(src + 4);
        *(uint2*)&tile[tok][sg] = v0;
        *(uint2*)&tile[tok][sg + 4] = v1;
    }
    __syncthreads();
    const int lane = tid & 63, dg = tid >> 6;
    size_t obase = ((size_t)(b * H_NUM + h) * DK) * S_LEN + s0 + lane;
#pragma unroll
    for (int i = 0; i < 16; ++i) {
        int d = dg * 16 + i;
        VT[obase + (size_t)d * S_LEN] = tile[lane][d];
    }
}

// ---------------------------------------------------------------------------
// MFMA flash attention, all-bf16 inputs via global_load_lds.
// Q pre-scaled by 0.125 (folded into Q-GEMM epilogue).
// Tiles [64][64] bf16, XOR seg-swizzle (seg^(row&7)) folded into staging addr.
// ---------------------------------------------------------------------------
__global__ __launch_bounds__(256, 4) void attn_mfma(
    const unsigned short* __restrict__ Q, const unsigned short* __restrict__ K,
    const unsigned short* __restrict__ VT, unsigned short* __restrict__ O)
{
    __shared__ __align__(16) unsigned short Qs[64][64];
    __shared__ __align__(16) unsigned short Ks[64][64];
    __shared__ __align__(16) unsigned short Vs[64][64];   // [d][key]
    __shared__ __align__(16) unsigned short Ps[4][16][72];

    const int qt = (int)gridDim.x - 1 - (int)blockIdx.x;  // heaviest first
    const int q0 = qt * 64;
    const int h = blockIdx.y, b = blockIdx.z;
    const int tid = threadIdx.x, w = tid >> 6, lane = tid & 63;
    const int quad = lane >> 4, cid = lane & 15;

    // staging: 1 KB chunk = 8 rows x 128 B; lane: row=ch*8+lane/8, seg=lane%8
    const int srow = lane >> 3;
    const int sw = ((lane & 7) ^ srow) * 8;   // swizzled logical bf16 col

#define AFRAG(buf, r, s) (*(const bf8*)&buf[r][(((s) ^ ((r) & 7)) * 8)])

    const unsigned short* qg =
        Q + ((size_t)b * S_LEN + q0 + w * 16 + srow) * U_DIM + h * DK + sw;
    gl2lds16(qg, &Qs[w * 16][0]);
    gl2lds16(qg + 8 * U_DIM, &Qs[w * 16 + 8][0]);
    __syncthreads();

    bf8 qf0 = AFRAG(Qs, w * 16 + cid, quad);
    bf8 qf1 = AFRAG(Qs, w * 16 + cid, 4 + quad);

    f4 o[4] = {};
    float m_i[4], l_i[4];
#pragma unroll
    for (int i = 0; i < 4; ++i) { m_i[i] = -INFINITY; l_i[i] = 0.0f; }

    const int lastkb = q0 >> 6;
    const unsigned short* kg =
        K + ((size_t)b * S_LEN + w * 16 + srow) * U_DIM + h * DK + sw;
    const unsigned short* vg =
        VT + ((size_t)(b * H_NUM + h) * DK + w * 16 + srow) * S_LEN + sw;

    for (int kb = 0; kb <= lastkb; ++kb) {
        __syncthreads();   // all waves done with previous Ks/Vs
        const unsigned short* kk = kg + (size_t)kb * 64 * U_DIM;
        gl2lds16(kk, &Ks[w * 16][0]);
        gl2lds16(kk + 8 * U_DIM, &Ks[w * 16 + 8][0]);
        const unsigned short* vv = vg + kb * 64;
        gl2lds16(vv, &Vs[w * 16][0]);
        gl2lds16(vv + 8 * S_LEN, &Vs[w * 16 + 8][0]);
        __syncthreads();

        // ---- S = Q K^T ----
        f4 sc[4];
#pragma unroll
        for (int t = 0; t < 4; ++t) {
            bf8 k0f = AFRAG(Ks, t * 16 + cid, quad);
            bf8 k1f = AFRAG(Ks, t * 16 + cid, 4 + quad);
            f4 acc = {};
            acc = __builtin_amdgcn_mfma_f32_16x16x32_bf16(qf0, k0f, acc, 0, 0, 0);
            acc = __builtin_amdgcn_mfma_f32_16x16x32_bf16(qf1, k1f, acc, 0, 0, 0);
            sc[t] = acc;
        }

        // ---- causal mask (diagonal block only) ----
        if (kb == lastkb) {
#pragma unroll
            for (int t = 0; t < 4; ++t) {
                int col = kb * 64 + t * 16 + cid;
#pragma unroll
                for (int i = 0; i < 4; ++i) {
                    int row = q0 + w * 16 + quad * 4 + i;
                    if (col > row) sc[t][i] = -1e30f;
                }
            }
        }

        // ---- online softmax ----
        float alpha_[4];
#pragma unroll
        for (int i = 0; i < 4; ++i) {
            float mx = fmaxf(fmaxf(sc[0][i], sc[1][i]), fmaxf(sc[2][i], sc[3][i]));
            mx = fmaxf(mx, __shfl_xor(mx, 1));
            mx = fmaxf(mx, __shfl_xor(mx, 2));
            mx = fmaxf(mx, __shfl_xor(mx, 4));
            mx = fmaxf(mx, __shfl_xor(mx, 8));
            float mnew = fmaxf(m_i[i], mx);
            alpha_[i] = __expf(m_i[i] - mnew);
            m_i[i] = mnew;
            float rs = 0.0f;
#pragma unroll
            for (int t = 0; t < 4; ++t) {
                float p = __expf(sc[t][i] - mnew);
                sc[t][i] = p;
                rs += p;
            }
            rs += __shfl_xor(rs, 1);
            rs += __shfl_xor(rs, 2);
            rs += __shfl_xor(rs, 4);
            rs += __shfl_xor(rs, 8);
            l_i[i] = l_i[i] * alpha_[i] + rs;
        }

        // ---- P: C-layout -> LDS -> A-layout ----
#pragma unroll
        for (int t = 0; t < 4; ++t)
#pragma unroll
            for (int i = 0; i < 4; ++i)
                Ps[w][quad * 4 + i][t * 16 + cid] = f2bf(sc[t][i]);

        bf8 p0 = *(const bf8*)&Ps[w][cid][quad * 8];
        bf8 p1 = *(const bf8*)&Ps[w][cid][32 + quad * 8];

        // ---- O = O*alpha + P V ----
#pragma unroll
        for (int t = 0; t < 4; ++t) {
#pragma unroll
            for (int i = 0; i < 4; ++i) o[t][i] *= alpha_[i];
            bf8 v0f = AFRAG(Vs, t * 16 + cid, quad);
            bf8 v1f = AFRAG(Vs, t * 16 + cid, 4 + quad);
            o[t] = __builtin_amdgcn_mfma_f32_16x16x32_bf16(p0, v0f, o[t], 0, 0, 0);
            o[t] = __builtin_amdgcn_mfma_f32_16x16x32_bf16(p1, v1f, o[t], 0, 0, 0);
        }
    }

    // ---- epilogue: O/l -> bf16 [b,s,u] ----
#pragma unroll
    for (int i = 0; i < 4; ++i) {
        float inv = 1.0f / l_i[i];
        int rowg = q0 + w * 16 + quad * 4 + i;
        size_t rbase = ((size_t)b * S_LEN + rowg) * U_DIM + h * DK;
#pragma unroll
        for (int t = 0; t < 4; ++t)
            O[rbase + t * 16 + cid] = f2bf(o[t][i] * inv);
    }
}

// ---------------------------------------------------------------------------
// ws layout (bf16): xq|xk|xv (8MB ea) | wq|wk|wv|wo (2MB ea) |
//                   qg|kg|vg|vt|ao (8MB ea)  = 72 MB total.
// ---------------------------------------------------------------------------
extern "C" void kernel_launch(void* const* d_in, const int* in_sizes, int n_in,
                              void* d_out, int out_size, void* d_ws, size_t ws_size,
                              hipStream_t stream)
{
    const float* query = (const float*)d_in[0];
    const float* key   = (const float*)d_in[1];
    const float* value = (const float*)d_in[2];
    const float* Wq = (const float*)d_in[4];
    const float* bq = (const float*)d_in[5];
    const float* Wk = (const float*)d_in[6];
    const float* bk = (const float*)d_in[7];
    const float* Wv = (const float*)d_in[8];
    const float* bv = (const float*)d_in[9];
    const float* Wo = (const float*)d_in[10];
    const float* bo = (const float*)d_in[11];
    float* out = (float*)d_out;

    const size_t ACT = (size_t)M_TOT * U_DIM;   // 4M elements
    const size_t WT  = (size_t)U_DIM * U_DIM;   // 1M elements

    unsigned short* xq  = (unsigned short*)d_ws;
    unsigned short* xk  = xq + ACT;
    unsigned short* xv  = xk + ACT;
    unsigned short* wqb = xv + ACT;
    unsigned short* wkb = wqb + WT;
    unsigned short* wvb = wkb + WT;
    unsigned short* wob = wvb + WT;
    unsigned short* qg  = wob + WT;
    unsigned short* kg  = qg + ACT;
    unsigned short* vg  = kg + ACT;
    unsigned short* vt  = vg + ACT;
    unsigned short* ao  = vt + ACT;

    // 1. fp32 -> bf16 conversions
    CvtArgs ca;
    ca.src[0] = query; ca.dst[0] = xq;  ca.n[0] = (int)ACT;
    ca.src[1] = key;   ca.dst[1] = xk;  ca.n[1] = (int)ACT;
    ca.src[2] = value; ca.dst[2] = xv;  ca.n[2] = (int)ACT;
    ca.src[3] = Wq;    ca.dst[3] = wqb; ca.n[3] = (int)WT;
    ca.src[4] = Wk;    ca.dst[4] = wkb; ca.n[4] = (int)WT;
    ca.src[5] = Wv;    ca.dst[5] = wvb; ca.n[5] = (int)WT;
    ca.src[6] = Wo;    ca.dst[6] = wob; ca.n[6] = (int)WT;
    convert_bf16<<<dim3(ACT / (256 * 8), 7), 256, 0, stream>>>(ca);

    // 2. fused QKV GEMM (768 blocks = 3/CU). Q scaled by 1/sqrt(DK).
    QkvArgs ga;
    ga.A[0] = xq; ga.W[0] = wqb; ga.bias[0] = bq; ga.C[0] = qg; ga.scale[0] = 0.125f;
    ga.A[1] = xk; ga.W[1] = wkb; ga.bias[1] = bk; ga.C[1] = kg; ga.scale[1] = 1.0f;
    ga.A[2] = xv; ga.W[2] = wvb; ga.bias[2] = bv; ga.C[2] = vg; ga.scale[2] = 1.0f;
    gemm_qkv<<<dim3(U_DIM / 128, M_TOT / 128, 3), 256, 0, stream>>>(ga);

    // 3. V -> V^T (bf16)
    transpose_v<<<dim3(S_LEN / 64, H_NUM, B_NUM), 256, 0, stream>>>(vg, vt);

    // 4. flash attention
    attn_mfma<<<dim3(S_LEN / 64, H_NUM, B_NUM), 256, 0, stream>>>(qg, kg, vt, ao);

    // 5. output projection (fp32 out)
    gemm_obf<<<dim3(U_DIM / 128, M_TOT / 128), 256, 0, stream>>>(ao, wob, bo, out);
}